// Round 11
// baseline (177.154 us; speedup 1.0000x reference)
//
#include <hip/hip_runtime.h>
#include <stdint.h>

// S=8, N=4096, F_IN=F_OUT=128
constexpr int N  = 4096;
constexpr int F  = 128;
constexpr int S  = 8;

typedef float f4  __attribute__((ext_vector_type(4)));
typedef short bf16x8 __attribute__((ext_vector_type(8)));
typedef unsigned short us4 __attribute__((ext_vector_type(4)));

__device__ __forceinline__ unsigned short f2bf(float f) {
  union { float f; unsigned int u; } v; v.f = f;
  unsigned int u = v.u + 0x7FFFu + ((v.u >> 16) & 1u);  // RNE
  return (unsigned short)(u >> 16);
}

__device__ __forceinline__ void bar_sync() {
  asm volatile("s_waitcnt lgkmcnt(0)" ::: "memory");
  __builtin_amdgcn_s_barrier();
  asm volatile("" ::: "memory");
}
__device__ __forceinline__ void vm_drain() {
  asm volatile("s_waitcnt vmcnt(0)" ::: "memory");
}
__device__ __forceinline__ void vm_wait9() {
  asm volatile("s_waitcnt vmcnt(9)" ::: "memory");
}
__device__ __forceinline__ void vm_wait8() {
  asm volatile("s_waitcnt vmcnt(8)" ::: "memory");
}

// async global->LDS, 16B/lane; LDS dest = wave-uniform base + lane*16.
__device__ __forceinline__ void gload_lds16(const void* g, void* l) {
  __builtin_amdgcn_global_load_lds(
      (const __attribute__((address_space(1))) void*)g,
      (__attribute__((address_space(3))) void*)l, 16, 0, 0);
}

// ---------------- kernel 0: xT[f][k] = bf16(x[k][f]) ----------------
__global__ __launch_bounds__(256, 2) void ggd_xt(
    const float* __restrict__ x, unsigned short* __restrict__ xT) {
  __shared__ float xl[64][132];       // +4 pad: conflict-free column reads
  const int t  = threadIdx.x;
  const int k0 = blockIdx.x * 64;
  {
    const int kr = t >> 2, fs = (t & 3) * 32;
    const float* src = x + (size_t)(k0 + kr) * F + fs;
#pragma unroll
    for (int i = 0; i < 8; ++i)
      *(f4*)&xl[kr][fs + i * 4] = *(const f4*)(src + i * 4);
  }
  __syncthreads();
  {
    const int f = t >> 1, kh = (t & 1) * 32;
    us4 o[8];
#pragma unroll
    for (int i = 0; i < 32; ++i)
      o[i >> 2][i & 3] = f2bf(xl[kh + i][f]);
    unsigned short* dst = xT + (size_t)f * N + k0 + kh;
#pragma unroll
    for (int j = 0; j < 8; ++j)
      *(us4*)(dst + j * 4) = o[j];
  }
}

// ------- kernel 1: pure-streaming q-gen (the 604 MB pass) -------
// q stored bf16, row-major, k pre-swizzled: storage[r][k^((r&7)<<3)] = q[r][k]
__global__ __launch_bounds__(256, 4) void ggd_qgen(
    const float* __restrict__ theta,
    const float* __restrict__ Ts,     // [S][N][N]
    const float* __restrict__ a,      // [N][N]
    unsigned short* __restrict__ q)   // [N][N] bf16 (swizzled)
{
  float th[S];
#pragma unroll
  for (int s = 0; s < S; ++s) th[s] = theta[s];

  constexpr int QF4 = N / 4;          // 1024 f4 per row
  constexpr int TOT = N * QF4;        // 4,194,304 f4 total
  const int tid    = blockIdx.x * 256 + threadIdx.x;
  const int stride = 1024 * 256;      // grid is fixed at 1024 blocks

  const f4* af4 = (const f4*)a;
  const f4* tf4 = (const f4*)Ts;
  us4* qs = (us4*)q;

#pragma unroll 1
  for (int i = tid; i < TOT; i += stride) {   // 16 iterations
    f4 tv[S];
#pragma unroll
    for (int s = 0; s < S; ++s) tv[s] = tf4[(size_t)s * TOT + i];
    f4 av = af4[i];
    f4 sum;
#pragma unroll
    for (int j = 0; j < 4; ++j) sum[j] = th[0] * tv[0][j];
#pragma unroll
    for (int s = 1; s < S; ++s)
#pragma unroll
      for (int j = 0; j < 4; ++j) sum[j] = fmaf(th[s], tv[s][j], sum[j]);
    us4 o;
#pragma unroll
    for (int j = 0; j < 4; ++j) o[j] = f2bf(av[j] * sum[j]);
    const int r  = i >> 10;           // row
    const int k4 = i & (QF4 - 1);     // f4-index within row
    qs[(size_t)r * QF4 + (k4 ^ ((r & 7) << 1))] = o;  // element-k ^ (r&7)<<3
  }
}

// ------- kernel 2: GEMM (q @ x) + PReLU + FC, depth-2 pipeline -------
__global__ __launch_bounds__(256, 1) void ggd_gemm(
    const unsigned short* __restrict__ q,   // [N][N] bf16, k-swizzled
    const unsigned short* __restrict__ xT,  // [F][N] bf16
    const float* __restrict__ W,            // [F][F] row-major [fo][fi]
    const float* __restrict__ bfc,          // [F]
    const float* __restrict__ alpha,        // [F]
    float* __restrict__ out)                // [N][F]
{
  __shared__ unsigned short qt[4][16][128];  // 16 KB quad-buffered
  __shared__ float p_lds[16 * F];            // 8 KB epilogue

  const int t = threadIdx.x, wave = t >> 6, lane = t & 63;
  const int n0 = blockIdx.x * 16;
  constexpr int NC = N / 128;                // 32 chunks

  // stage q tile [16][128] bf16: wave w stages rows 4w..4w+3, LINEAR read
  // of the pre-swizzled storage -> LDS holds the swizzled tile.
  auto stage_q = [&](int c) {
    const int row = wave * 4 + (lane >> 4);
    const unsigned short* src =
        q + (size_t)(n0 + row) * N + c * 128 + (lane & 15) * 8;
    gload_lds16(src, &qt[c & 3][wave * 4][0]);
  };

  struct BB { bf16x8 v[8]; };   // [ftile i][kstep h] -> v[i*4+h]
  auto bload = [&](int c, BB& B) {
#pragma unroll
    for (int i = 0; i < 2; ++i) {
      const unsigned short* fp =
          xT + (size_t)((wave * 2 + i) * 16 + (lane & 15)) * N + c * 128 +
          (lane >> 4) * 8;
#pragma unroll
      for (int h = 0; h < 4; ++h)
        B.v[i * 4 + h] = *(const bf16x8*)(fp + h * 32);
    }
  };

  f4 acc[2];
#pragma unroll
  for (int i = 0; i < 2; ++i) acc[i] = (f4)(0.f);

  // A-frag read undoes the swizzle: k-offset ^ ((row&7)<<3), row = lane&15.
  auto compute = [&](int c, const BB& B) {
    const unsigned short* qb = &qt[c & 3][0][0];
    const int rsw = (lane & 7) << 3;
#pragma unroll
    for (int h = 0; h < 4; ++h) {
      bf16x8 af = *(const bf16x8*)(
          qb + (lane & 15) * 128 + ((h * 32 + (lane >> 4) * 8) ^ rsw));
      acc[0] = __builtin_amdgcn_mfma_f32_16x16x32_bf16(af, B.v[h],     acc[0], 0, 0, 0);
      acc[1] = __builtin_amdgcn_mfma_f32_16x16x32_bf16(af, B.v[4 + h], acc[1], 0, 0, 0);
    }
  };

  // hoist epilogue scalars
  const int fo0_ = (wave * 2 + 0) * 16 + (lane & 15);
  const int fo1_ = (wave * 2 + 1) * 16 + (lane & 15);
  const float al0 = alpha[fo0_];
  const float al1 = alpha[fo1_];

  BB bE, bO;

  // prologue: q chunks 0,1 staged; B(0) in regs
  stage_q(0);
  stage_q(1);
  bload(0, bE);

  // steady state: per iter issue {1 stage + 8 bload}; wait(9) = one full
  // iteration of latency cover; barrier makes cross-wave staging visible.
  for (int c = 0; c < NC - 2; c += 2) {        // c = 0,2,...,28
    {
      stage_q(c + 2);
      bload(c + 1, bO);
      vm_wait9();
      bar_sync();
      compute(c, bE);
    }
    {
      stage_q(c + 3);
      bload(c + 2, bE);
      vm_wait9();
      bar_sync();
      compute(c + 1, bO);
    }
  }
  // tail: c = 30, 31
  {
    bload(NC - 1, bO);
    vm_wait8();
    bar_sync();
    compute(NC - 2, bE);
  }
  {
    vm_drain();
    bar_sync();
    compute(NC - 1, bO);
  }

  // ---- epilogue: PReLU -> p_lds ----
#pragma unroll
  for (int i = 0; i < 2; ++i) {
    const int fo = (i == 0) ? fo0_ : fo1_;
    const float al = (i == 0) ? al0 : al1;
#pragma unroll
    for (int r = 0; r < 4; ++r) {
      float v = acc[i][r];
      v = v >= 0.f ? v : al * v;
      p_lds[((lane >> 4) * 4 + r) * F + fo] = v;
    }
  }
  bar_sync();

  // ---- FC: out[n][fo] = b[fo] + sum_fi p[n][fi] * W[fo][fi] ----
  const int r2  = t >> 5;             // 0..7 -> rows {r2, r2+8}
  const int fo0 = (t & 31) * 4;
  f4 accA = *(const f4*)(bfc + fo0);
  f4 accB = accA;
#pragma unroll 4
  for (int fi4 = 0; fi4 < F / 4; ++fi4) {
    f4 pA = *(const f4*)&p_lds[r2 * F + fi4 * 4];
    f4 pB = *(const f4*)&p_lds[(r2 + 8) * F + fi4 * 4];
#pragma unroll
    for (int e = 0; e < 4; ++e) {
      f4 wv = *(const f4*)(W + (size_t)(fo0 + e) * F + fi4 * 4);
      accA[e] = fmaf(pA[0], wv[0], fmaf(pA[1], wv[1],
                fmaf(pA[2], wv[2], fmaf(pA[3], wv[3], accA[e]))));
      accB[e] = fmaf(pB[0], wv[0], fmaf(pB[1], wv[1],
                fmaf(pB[2], wv[2], fmaf(pB[3], wv[3], accB[e]))));
    }
  }
  *(f4*)(out + (size_t)(n0 + r2) * F + fo0)     = accA;
  *(f4*)(out + (size_t)(n0 + r2 + 8) * F + fo0) = accB;
}

// -------- fallback (ws too small): round-1 fused kernel, no ws --------
__global__ __launch_bounds__(256, 1) void ggd_fused_fb(
    const float* __restrict__ theta, const float* __restrict__ Ts,
    const float* __restrict__ x, const float* __restrict__ a,
    const float* __restrict__ W, const float* __restrict__ bfc,
    const float* __restrict__ alpha, float* __restrict__ out) {
  constexpr int BM = 16, BK = 64, NCF = N / BK;
  __shared__ float q_lds[2][BM][BK];
  __shared__ float p_lds[BM][F];
  const int t  = threadIdx.x;
  const int n0 = blockIdx.x * BM;
  float th[S];
#pragma unroll
  for (int s = 0; s < S; ++s) th[s] = theta[s];
  const int qr = t >> 4;
  const int qk = (t & 15) << 2;
  const size_t rowOff  = (size_t)(n0 + qr) * N;
  const size_t sliceSz = (size_t)N * N;
  const int tx = t & 31, ty = t >> 5;
  const int r0 = ty * 2, r1 = r0 + 1;
  f4 acc0 = (f4)(0.f), acc1 = (f4)(0.f);
  f4 tv[S]; f4 av;
  auto loadc = [&](int c) {
    const size_t off = rowOff + (size_t)c * BK + qk;
    av = *(const f4*)(a + off);
#pragma unroll
    for (int s = 0; s < S; ++s)
      tv[s] = *(const f4*)(Ts + (size_t)s * sliceSz + off);
  };
  auto qstore = [&](int buf) {
    f4 qv;
#pragma unroll
    for (int j = 0; j < 4; ++j) {
      float sum = th[0] * tv[0][j];
#pragma unroll
      for (int s = 1; s < S; ++s) sum = fmaf(th[s], tv[s][j], sum);
      qv[j] = av[j] * sum;
    }
    *(f4*)&q_lds[buf][qr][qk] = qv;
  };
  loadc(0); qstore(0);
  for (int c = 0; c < NCF; ++c) {
    const int buf = c & 1;
    if (c + 1 < NCF) loadc(c + 1);
    bar_sync();
    const float* xp = x + (size_t)c * BK * F + tx * 4;
#pragma unroll 4
    for (int kk4 = 0; kk4 < BK / 4; ++kk4) {
      f4 q0 = *(const f4*)&q_lds[buf][r0][kk4 * 4];
      f4 q1 = *(const f4*)&q_lds[buf][r1][kk4 * 4];
#pragma unroll
      for (int j = 0; j < 4; ++j) {
        f4 xv = *(const f4*)(xp + (size_t)(kk4 * 4 + j) * F);
#pragma unroll
        for (int e = 0; e < 4; ++e) {
          acc0[e] = fmaf(q0[j], xv[e], acc0[e]);
          acc1[e] = fmaf(q1[j], xv[e], acc1[e]);
        }
      }
    }
    if (c + 1 < NCF) qstore(buf ^ 1);
  }
  {
    f4 al = *(const f4*)(alpha + tx * 4);
#pragma unroll
    for (int j = 0; j < 4; ++j) {
      acc0[j] = acc0[j] >= 0.f ? acc0[j] : al[j] * acc0[j];
      acc1[j] = acc1[j] >= 0.f ? acc1[j] : al[j] * acc1[j];
    }
  }
  *(f4*)&p_lds[r0][tx * 4] = acc0;
  *(f4*)&p_lds[r1][tx * 4] = acc1;
  bar_sync();
  const int rr  = t >> 4;
  const int fo0 = (t & 15) * 8;
  float accF[8];
  {
    f4 b0 = *(const f4*)(bfc + fo0);
    f4 b1 = *(const f4*)(bfc + fo0 + 4);
#pragma unroll
    for (int j = 0; j < 4; ++j) { accF[j] = b0[j]; accF[4 + j] = b1[j]; }
  }
#pragma unroll 8
  for (int fi4 = 0; fi4 < F / 4; ++fi4) {
    f4 p4 = *(const f4*)&p_lds[rr][fi4 * 4];
#pragma unroll
    for (int j = 0; j < 8; ++j) {
      f4 w4 = *(const f4*)(W + (size_t)(fo0 + j) * F + fi4 * 4);
      accF[j] = fmaf(p4[0], w4[0], fmaf(p4[1], w4[1],
                fmaf(p4[2], w4[2], fmaf(p4[3], w4[3], accF[j]))));
    }
  }
  f4 o0, o1;
#pragma unroll
  for (int j = 0; j < 4; ++j) { o0[j] = accF[j]; o1[j] = accF[4 + j]; }
  float* op = out + (size_t)(n0 + rr) * F + fo0;
  *(f4*)op       = o0;
  *(f4*)(op + 4) = o1;
}

extern "C" void kernel_launch(void* const* d_in, const int* in_sizes, int n_in,
                              void* d_out, int out_size, void* d_ws, size_t ws_size,
                              hipStream_t stream) {
  const float* theta = (const float*)d_in[0];
  const float* Ts    = (const float*)d_in[1];
  const float* x     = (const float*)d_in[2];
  const float* a     = (const float*)d_in[3];
  const float* W     = (const float*)d_in[4];
  const float* bfc   = (const float*)d_in[5];
  const float* alpha = (const float*)d_in[6];
  float* out = (float*)d_out;

  const size_t q_bytes  = (size_t)N * N * 2;   // 33.55 MB bf16
  const size_t xt_bytes = (size_t)N * F * 2;   // 1.05 MB bf16
  if (ws_size >= q_bytes + xt_bytes && d_ws != nullptr) {
    unsigned short* qbuf = (unsigned short*)d_ws;
    unsigned short* xT   = (unsigned short*)((char*)d_ws + q_bytes);
    ggd_xt  <<<dim3(N / 64), dim3(256), 0, stream>>>(x, xT);
    ggd_qgen<<<dim3(1024),   dim3(256), 0, stream>>>(theta, Ts, a, qbuf);
    ggd_gemm<<<dim3(N / 16), dim3(256), 0, stream>>>(qbuf, xT, W, bfc, alpha, out);
  } else {
    ggd_fused_fb<<<dim3(N / 16), dim3(256), 0, stream>>>(
        theta, Ts, x, a, W, bfc, alpha, out);
  }
}

// Round 12
// 170.856 us; speedup vs baseline: 1.0369x; 1.0369x over previous
//
#include <hip/hip_runtime.h>
#include <stdint.h>

// S=8, N=4096, F_IN=F_OUT=128
constexpr int N  = 4096;
constexpr int F  = 128;
constexpr int S  = 8;
constexpr int BM = 16;             // rows per block
constexpr int BK = 256;            // k per superchunk
constexpr int NCH = N / BK;        // 16 superchunks
constexpr int NPAIR = NCH * 4;     // 64 slice-pair stage steps
constexpr int NT = 512;            // 8 waves

typedef float f4  __attribute__((ext_vector_type(4)));
typedef short bf16x8 __attribute__((ext_vector_type(8)));
typedef unsigned short us4 __attribute__((ext_vector_type(4)));

__device__ __forceinline__ unsigned short f2bf(float f) {
  union { float f; unsigned int u; } v; v.f = f;
  unsigned int u = v.u + 0x7FFFu + ((v.u >> 16) & 1u);  // RNE
  return (unsigned short)(u >> 16);
}

__device__ __forceinline__ void bar_sync() {
  asm volatile("s_waitcnt lgkmcnt(0)" ::: "memory");
  __builtin_amdgcn_s_barrier();
  asm volatile("" ::: "memory");
}
__device__ __forceinline__ void vm_wait0() {
  asm volatile("s_waitcnt vmcnt(0)" ::: "memory");
}
__device__ __forceinline__ void vm_wait4() {
  asm volatile("s_waitcnt vmcnt(4)" ::: "memory");
}

// async global->LDS, 16B/lane; LDS dest = wave-uniform base + lane*16.
__device__ __forceinline__ void gload_lds16(const void* g, void* l) {
  __builtin_amdgcn_global_load_lds(
      (const __attribute__((address_space(1))) void*)g,
      (__attribute__((address_space(3))) void*)l, 16, 0, 0);
}

// ---------------- kernel 0: xT[f][k] = bf16(x[k][f]) ----------------
__global__ __launch_bounds__(256, 2) void ggd_xt(
    const float* __restrict__ x, unsigned short* __restrict__ xT) {
  __shared__ float xl[64][132];
  const int t  = threadIdx.x;
  const int k0 = blockIdx.x * 64;
  {
    const int kr = t >> 2, fs = (t & 3) * 32;
    const float* src = x + (size_t)(k0 + kr) * F + fs;
#pragma unroll
    for (int i = 0; i < 8; ++i)
      *(f4*)&xl[kr][fs + i * 4] = *(const f4*)(src + i * 4);
  }
  __syncthreads();
  {
    const int f = t >> 1, kh = (t & 1) * 32;
    us4 o[8];
#pragma unroll
    for (int i = 0; i < 32; ++i)
      o[i >> 2][i & 3] = f2bf(xl[kh + i][f]);
    unsigned short* dst = xT + (size_t)f * N + k0 + kh;
#pragma unroll
    for (int j = 0; j < 8; ++j)
      *(us4*)(dst + j * 4) = o[j];
  }
}

// ---- kernel 1: fused full-K diffuse + PReLU + FC, 1-KB T streams ----
__global__ __launch_bounds__(NT, 1) void ggd_main(
    const float* __restrict__ theta,
    const float* __restrict__ Ts,     // [S][N][N]
    const unsigned short* __restrict__ xT,  // [F][N] bf16
    const float* __restrict__ a,      // [N][N]
    const float* __restrict__ W,      // [F][F]
    const float* __restrict__ bfc,    // [F]
    const float* __restrict__ alpha,  // [F]
    float* __restrict__ out)          // [N][F]
{
  // 3 slots x 2 slices x [16 rows][256 k] f32 = 96 KB (source-swizzled)
  __shared__ float rawT[3][2][BM][BK];
  __shared__ unsigned short q_lds[BM][BK];  // 8 KB bf16, k-swizzled
  __shared__ float p_lds[BM][F];            // 8 KB epilogue

  const int t    = threadIdx.x;
  const int n0   = blockIdx.x * BM;
  const int wave = t >> 6, lane = t & 63;
  const size_t slice = (size_t)N * N;

  float th[S];
#pragma unroll
  for (int s = 0; s < S; ++s) th[s] = theta[s];

  // accum/qfinish mapping: row = t>>5 (0..15), f4-cols m = (t&31) + 32j
  const int arow = t >> 5;
  const int m0   = t & 31;
  const int rsw  = 2 * (arow & 7);        // f4-granular swizzle for this row
  const int ms0  = m0 ^ rsw;              // pre-swizzled f4 index base

  // stage pair (cq, pq) -> slot: instr idx = wave*4+j: sl = idx>>4, row=idx&15
  auto stage = [&](int cq, int pq, int slot) {
    const size_t colb = (size_t)cq * BK;
#pragma unroll
    for (int j = 0; j < 4; ++j) {
      const int idx = wave * 4 + j;       // 0..31
      const int sl  = idx >> 4;           // 0..1
      const int row = idx & 15;
      const int s   = 2 * pq + sl;
      // source f4 index permuted so LDS[d] = T[d ^ 2*(row&7)]
      const float* src = Ts + (size_t)s * slice + (size_t)(n0 + row) * N +
                         colb + 4 * (lane ^ (2 * (row & 7)));
      gload_lds16(src, &rawT[slot][sl][row][0]);
    }
  };

  f4 av[2];
  auto aload = [&](int c) {
#pragma unroll
    for (int j = 0; j < 2; ++j)
      av[j] = *(const f4*)(a + (size_t)(n0 + arow) * N + c * BK +
                           4 * (m0 + 32 * j));
  };

  f4 acc = (f4)(0.f);                     // full-K MFMA accumulator

  int cm3 = 0;                            // (c*4) % 3

  // prologue
  aload(0);
  stage(0, 0, 0);                         // pair 0 -> slot 0
  stage(0, 1, 1);                         // pair 1 -> slot 1

  for (int c = 0; c < NCH; ++c) {
    f4 qacc[2] = {(f4)(0.f), (f4)(0.f)};

#pragma unroll
    for (int p = 0; p < 4; ++p) {
      const int P = c * 4 + p;
      if (P == NPAIR - 1) vm_wait0(); else vm_wait4();
      bar_sync();
      if (P + 2 < NPAIR) {
        const int Q  = P + 2;
        const int cq = (p < 2) ? c : c + 1;
        const int pq = (p < 2) ? p + 2 : p - 2;
        stage(cq, pq, (cm3 + p + 2) % 3);
      }
      // accumulate slices 2p, 2p+1 from slot (cm3+p)%3
      {
        const int slot = (cm3 + p) % 3;
#pragma unroll
        for (int sl = 0; sl < 2; ++sl) {
          const float* base = &rawT[slot][sl][arow][0];
          const float ths = th[2 * p + sl];
#pragma unroll
          for (int j = 0; j < 2; ++j) {
            f4 tv = *(const f4*)(base + 4 * (ms0 + 32 * j));
#pragma unroll
            for (int e = 0; e < 4; ++e)
              qacc[j][e] = fmaf(ths, tv[e], qacc[j][e]);
          }
        }
      }
    }

    // ---- q-finish: mask by a, bf16, swizzled store ----
#pragma unroll
    for (int j = 0; j < 2; ++j) {
      us4 o;
#pragma unroll
      for (int e = 0; e < 4; ++e) o[e] = f2bf(av[j][e] * qacc[j][e]);
      const int elem = (4 * (m0 + 32 * j)) ^ (8 * (arow & 7));
      *(us4*)&q_lds[arow][elem] = o;
    }
    bar_sync();

    // ---- B-fragments (L2-hot xT), next-chunk a, then 8 MFMA ----
    bf16x8 B[8];
    {
      const unsigned short* fp =
          xT + (size_t)(wave * 16 + (lane & 15)) * N + c * BK +
          (lane >> 4) * 8;
#pragma unroll
      for (int k = 0; k < 8; ++k) B[k] = *(const bf16x8*)(fp + k * 32);
    }
    if (c + 1 < NCH) aload(c + 1);
#pragma unroll
    for (int k = 0; k < 8; ++k) {
      const int elem = (k * 32 + (lane >> 4) * 8) ^ ((lane & 7) << 3);
      bf16x8 af = *(const bf16x8*)&q_lds[lane & 15][elem];
      acc = __builtin_amdgcn_mfma_f32_16x16x32_bf16(af, B[k], acc, 0, 0, 0);
    }

    cm3 = (cm3 + 1) % 3;                  // (c*4)%3 advances by 1
  }

  // ---- epilogue: PReLU -> p_lds; C/D: col=lane&15, row=(lane>>4)*4+r ----
  {
    const int fo = wave * 16 + (lane & 15);
    const float al = alpha[fo];
#pragma unroll
    for (int r = 0; r < 4; ++r) {
      float v = acc[r];
      v = v >= 0.f ? v : al * v;
      p_lds[(lane >> 4) * 4 + r][fo] = v;
    }
  }
  bar_sync();

  // ---- FC: out[n][fo] = b + sum_fi p[n][fi]*W[fo][fi] ----
  {
    const int r2  = t >> 5;               // 0..15
    const int fo4 = (t & 31) * 4;
    f4 accF = *(const f4*)(bfc + fo4);
#pragma unroll 4
    for (int fi4 = 0; fi4 < F / 4; ++fi4) {
      f4 pv = *(const f4*)&p_lds[r2][fi4 * 4];
#pragma unroll
      for (int e = 0; e < 4; ++e) {
        f4 wv = *(const f4*)(W + (size_t)(fo4 + e) * F + fi4 * 4);
        accF[e] = fmaf(pv[0], wv[0], fmaf(pv[1], wv[1],
                  fmaf(pv[2], wv[2], fmaf(pv[3], wv[3], accF[e]))));
      }
    }
    *(f4*)(out + (size_t)(n0 + r2) * F + fo4) = accF;
  }
}

// -------- fallback (ws too small): round-1 fused kernel --------
__global__ __launch_bounds__(256, 1) void ggd_fused_fb(
    const float* __restrict__ theta, const float* __restrict__ Ts,
    const float* __restrict__ x, const float* __restrict__ a,
    const float* __restrict__ W, const float* __restrict__ bfc,
    const float* __restrict__ alpha, float* __restrict__ out) {
  constexpr int BMf = 16, BKf = 64, NCF = N / BKf;
  __shared__ float q_l[2][BMf][BKf];
  __shared__ float p_l[BMf][F];
  const int t  = threadIdx.x;
  const int n0 = blockIdx.x * BMf;
  float th[S];
#pragma unroll
  for (int s = 0; s < S; ++s) th[s] = theta[s];
  const int qr = t >> 4, qk = (t & 15) << 2;
  const size_t rowOff = (size_t)(n0 + qr) * N, sliceSz = (size_t)N * N;
  const int tx = t & 31, ty = t >> 5;
  const int r0 = ty * 2, r1 = r0 + 1;
  f4 acc0 = (f4)(0.f), acc1 = (f4)(0.f);
  f4 tv[S]; f4 avv;
  auto loadc = [&](int c) {
    const size_t off = rowOff + (size_t)c * BKf + qk;
    avv = *(const f4*)(a + off);
#pragma unroll
    for (int s = 0; s < S; ++s)
      tv[s] = *(const f4*)(Ts + (size_t)s * sliceSz + off);
  };
  auto qstore = [&](int buf) {
    f4 qv;
#pragma unroll
    for (int j = 0; j < 4; ++j) {
      float sum = th[0] * tv[0][j];
#pragma unroll
      for (int s = 1; s < S; ++s) sum = fmaf(th[s], tv[s][j], sum);
      qv[j] = avv[j] * sum;
    }
    *(f4*)&q_l[buf][qr][qk] = qv;
  };
  loadc(0); qstore(0);
  for (int c = 0; c < NCF; ++c) {
    const int buf = c & 1;
    if (c + 1 < NCF) loadc(c + 1);
    bar_sync();
    const float* xp = x + (size_t)c * BKf * F + tx * 4;
#pragma unroll 4
    for (int kk4 = 0; kk4 < BKf / 4; ++kk4) {
      f4 q0 = *(const f4*)&q_l[buf][r0][kk4 * 4];
      f4 q1 = *(const f4*)&q_l[buf][r1][kk4 * 4];
#pragma unroll
      for (int j = 0; j < 4; ++j) {
        f4 xv = *(const f4*)(xp + (size_t)(kk4 * 4 + j) * F);
#pragma unroll
        for (int e = 0; e < 4; ++e) {
          acc0[e] = fmaf(q0[j], xv[e], acc0[e]);
          acc1[e] = fmaf(q1[j], xv[e], acc1[e]);
        }
      }
    }
    if (c + 1 < NCF) qstore(buf ^ 1);
  }
  {
    f4 al = *(const f4*)(alpha + tx * 4);
#pragma unroll
    for (int j = 0; j < 4; ++j) {
      acc0[j] = acc0[j] >= 0.f ? acc0[j] : al[j] * acc0[j];
      acc1[j] = acc1[j] >= 0.f ? acc1[j] : al[j] * acc1[j];
    }
  }
  *(f4*)&p_l[r0][tx * 4] = acc0;
  *(f4*)&p_l[r1][tx * 4] = acc1;
  bar_sync();
  const int rr = t >> 4, fo0 = (t & 15) * 8;
  float accF[8];
  {
    f4 b0 = *(const f4*)(bfc + fo0);
    f4 b1 = *(const f4*)(bfc + fo0 + 4);
#pragma unroll
    for (int j = 0; j < 4; ++j) { accF[j] = b0[j]; accF[4 + j] = b1[j]; }
  }
#pragma unroll 8
  for (int fi4 = 0; fi4 < F / 4; ++fi4) {
    f4 p4 = *(const f4*)&p_l[rr][fi4 * 4];
#pragma unroll
    for (int j = 0; j < 8; ++j) {
      f4 w4 = *(const f4*)(W + (size_t)(fo0 + j) * F + fi4 * 4);
      accF[j] = fmaf(p4[0], w4[0], fmaf(p4[1], w4[1],
                fmaf(p4[2], w4[2], fmaf(p4[3], w4[3], accF[j]))));
    }
  }
  f4 o0, o1;
#pragma unroll
  for (int j = 0; j < 4; ++j) { o0[j] = accF[j]; o1[j] = accF[4 + j]; }
  float* op = out + (size_t)(n0 + rr) * F + fo0;
  *(f4*)op       = o0;
  *(f4*)(op + 4) = o1;
}

extern "C" void kernel_launch(void* const* d_in, const int* in_sizes, int n_in,
                              void* d_out, int out_size, void* d_ws, size_t ws_size,
                              hipStream_t stream) {
  const float* theta = (const float*)d_in[0];
  const float* Ts    = (const float*)d_in[1];
  const float* x     = (const float*)d_in[2];
  const float* a     = (const float*)d_in[3];
  const float* W     = (const float*)d_in[4];
  const float* bfc   = (const float*)d_in[5];
  const float* alpha = (const float*)d_in[6];
  float* out = (float*)d_out;

  const size_t xt_bytes = (size_t)N * F * 2;   // 1 MB
  if (ws_size >= xt_bytes && d_ws != nullptr) {
    unsigned short* xT = (unsigned short*)d_ws;
    ggd_xt  <<<dim3(N / 64), dim3(256), 0, stream>>>(x, xT);
    ggd_main<<<dim3(N / BM), dim3(NT), 0, stream>>>(
        theta, Ts, xT, a, W, bfc, alpha, out);
  } else {
    ggd_fused_fb<<<dim3(N / 16), dim3(256), 0, stream>>>(
        theta, Ts, x, a, W, bfc, alpha, out);
  }
}